// Round 5
// baseline (518.764 us; speedup 1.0000x reference)
//
#include <hip/hip_runtime.h>

// Problem constants (B,O,I,D_out,D_in) = (512,10,1152,16,8)
#define BB 512
#define OO 10
#define II 1152
#define DD 16
#define EE 8
#define GB 32              // batches per block: 16 g-threads x 2 batches each
#define BOD (BB * OO * DD) // 81920 = elements of s[b,o,d]
#define WSLAB (II * DD * EE / 4) // float4s per o-slab of W

typedef float v2f __attribute__((ext_vector_type(2)));
typedef float v4f __attribute__((ext_vector_type(4)));

// Packed fp32 math (VOP3P; plain VALU, no DPP hazards).
__device__ __forceinline__ v2f pk_mul(v2f a, v2f b) {
    v2f d;
    asm("v_pk_mul_f32 %0, %1, %2" : "=v"(d) : "v"(a), "v"(b));
    return d;
}
__device__ __forceinline__ v2f pk_fma(v2f a, v2f b, v2f c) {
    v2f d;
    asm("v_pk_fma_f32 %0, %1, %2, %3" : "=v"(d) : "v"(a), "v"(b), "v"(c));
    return d;
}

// 8-element dot: W row (2 float4) . x row (2 float4).
__device__ __forceinline__ float dot8(v4f wa, v4f wb, v4f xa, v4f xb) {
    v2f p = pk_mul(wa.lo, xa.lo);
    p = pk_fma(wa.hi, xa.hi, p);
    p = pk_fma(wb.lo, xb.lo, p);
    p = pk_fma(wb.hi, xb.hi, p);
    return p.x + p.y;
}

// One DPP-shuffled add; compiler inserts required DPP hazard NOPs.
template <int CTRL>
__device__ __forceinline__ float dpp_add(float v) {
    int s = __builtin_amdgcn_update_dpp(0, __float_as_int(v), CTRL, 0xf, 0xf, true);
    return v + __int_as_float(s);
}
// Butterfly sum across the 16-lane d-group (d = lane&15), pure VALU.
__device__ __forceinline__ float dred16(float v) {
    v = dpp_add<0xB1>(v);    // xor1 (quad_perm[1,0,3,2])
    v = dpp_add<0x4E>(v);    // xor2 (quad_perm[2,3,0,1])
    v = dpp_add<0x141>(v);   // row_half_mirror == xor4 after 4-lane uniformity
    v = dpp_add<0x140>(v);   // row_mirror == xor8 after 8-lane uniformity
    return v;
}

__device__ __forceinline__ float squash_lane(float sv) {
    float sn = dred16(sv * sv);
    return sv * (sn / ((1.0f + sn) * sqrtf(sn)));
}

// One routing pass over an i-chunk. PASS=0: uniform c -> s. PASS=1: b=<v0,xh>.
// PASS=2: b=<v0+v1,xh>. Each thread owns 2 batches (b0, b0+16).
// ATOMIC=false: plain-store partials to s_out[ic*BOD + ...] (reduced later).
// ATOMIC=true : atomicAdd into dense s_out (fallback when ws is small).
template <int PASS, int IC, int MINW, bool ATOMIC>
__global__ __launch_bounds__(256, MINW)
void caps_pass(const float* __restrict__ x, const float* __restrict__ W,
               float* __restrict__ s_out,
               const float* __restrict__ s0, const float* __restrict__ s1) {
    constexpr int ILEN = II / IC;
    constexpr int XROW = ILEN * 2 + 1;   // padded LDS row stride (float4s)
    __shared__ v4f xlds[GB * XROW];

    const int tid = threadIdx.x;
    const int d = tid & 15;
    const int g = tid >> 4;           // 0..15
    const int bg = blockIdx.x / IC;   // batch group
    const int ic = blockIdx.x & (IC - 1);
    const int b0 = bg * GB + g;
    const int b1 = b0 + 16;
    const int i0 = ic * ILEN;

    // Stage x[bg*32 .. +31][i0 .. i0+ILEN-1][:] into LDS (coalesced float4)
    const v4f* x4 = (const v4f*)x;
    for (int k = tid; k < GB * ILEN * 2; k += 256) {
        const int gg = k / (ILEN * 2);
        const int rem = k - gg * (ILEN * 2);
        xlds[gg * XROW + rem] =
            x4[(size_t)(bg * GB + gg) * (II * EE / 4) + (size_t)i0 * 2 + rem];
    }

    constexpr float LOG2E = 1.44269504f;
    // vr = log2(e) * (squash(s0) [+ squash(s1)]) so softmax uses exp2 directly.
    float vr0[OO], vr1[OO];
    if constexpr (PASS >= 1) {
        #pragma unroll
        for (int o = 0; o < OO; o++) {
            float v = squash_lane(s0[(b0 * OO + o) * DD + d]);
            float w = squash_lane(s0[(b1 * OO + o) * DD + d]);
            if constexpr (PASS == 2) {
                v += squash_lane(s1[(b0 * OO + o) * DD + d]);
                w += squash_lane(s1[(b1 * OO + o) * DD + d]);
            }
            vr0[o] = v * LOG2E;
            vr1[o] = w * LOG2E;
        }
    }
    __syncthreads();

    float sa0[OO], sa1[OO];
    #pragma unroll
    for (int o = 0; o < OO; o++) { sa0[o] = 0.0f; sa1[o] = 0.0f; }

    const v4f* W4 = (const v4f*)W;
    int widx = (i0 * DD + d) * 2;   // float4 index inside an o-slab

    for (int ii = 0; ii < ILEN; ii++) {
        const v4f xa0 = xlds[g * XROW + ii * 2 + 0];
        const v4f xb0 = xlds[g * XROW + ii * 2 + 1];
        const v4f xa1 = xlds[(g + 16) * XROW + ii * 2 + 0];
        const v4f xb1 = xlds[(g + 16) * XROW + ii * 2 + 1];

        float xh0[OO], xh1[OO];
        #pragma unroll
        for (int o = 0; o < OO; o++) {
            const v4f wa = W4[o * WSLAB + widx];
            const v4f wb = W4[o * WSLAB + widx + 1];
            xh0[o] = dot8(wa, wb, xa0, xb0);  // W reused for both batches
            xh1[o] = dot8(wa, wb, xa1, xb1);
        }

        if constexpr (PASS == 0) {
            #pragma unroll
            for (int o = 0; o < OO; o++) { sa0[o] += xh0[o]; sa1[o] += xh1[o]; }
        } else {
            float e0[OO], e1[OO];
            float se0 = 0.0f, se1 = 0.0f;
            #pragma unroll
            for (int o = 0; o < OO; o++) {
                e0[o] = __builtin_amdgcn_exp2f(dred16(vr0[o] * xh0[o]));
                e1[o] = __builtin_amdgcn_exp2f(dred16(vr1[o] * xh1[o]));
                se0 += e0[o];
                se1 += e1[o];
            }
            const float inv0 = __builtin_amdgcn_rcpf(se0);
            const float inv1 = __builtin_amdgcn_rcpf(se1);
            #pragma unroll
            for (int o = 0; o < OO; o++) {
                sa0[o] = fmaf(e0[o] * inv0, xh0[o], sa0[o]);
                sa1[o] = fmaf(e1[o] * inv1, xh1[o], sa1[o]);
            }
        }
        widx += DD * 2;
    }

    if constexpr (ATOMIC) {
        const float scale = (PASS == 0) ? 0.1f : 1.0f;
        #pragma unroll
        for (int o = 0; o < OO; o++) {
            atomicAdd(&s_out[(b0 * OO + o) * DD + d], sa0[o] * scale);
            atomicAdd(&s_out[(b1 * OO + o) * DD + d], sa1[o] * scale);
        }
    } else {
        float* P = s_out + (size_t)ic * BOD;
        #pragma unroll
        for (int o = 0; o < OO; o++) {
            P[(b0 * OO + o) * DD + d] = sa0[o];
            P[(b1 * OO + o) * DD + d] = sa1[o];
        }
    }
}

// Reduce partials: s[idx] = scale * sum_ic P[ic][idx]. Deterministic, streaming.
template <int IC>
__global__ __launch_bounds__(256)
void caps_reduce(const float* __restrict__ P, float* __restrict__ s, float scale) {
    const int idx = blockIdx.x * 256 + threadIdx.x;
    float a = 0.0f;
    #pragma unroll 8
    for (int ic = 0; ic < IC; ic++) a += P[(size_t)ic * BOD + idx];
    s[idx] = a * scale;
}

// Finalize: outputs = squash(s2); idx = argmax_o ||outputs||; t = outputs[idx].
// FUSED: src is the partial array (reduce s2 on the fly); else src is dense s2.
// d_out layout: t [B,1,16] flat first, then outputs [B,10,16].
template <int IC, bool FUSED>
__global__ __launch_bounds__(192)
void caps_final(const float* __restrict__ src, float* __restrict__ out) {
    __shared__ float norml[12];
    const int b = blockIdx.x;
    const int tid = threadIdx.x;
    const int d = tid & 15;
    const int o = tid >> 4;  // 0..11, active o<10

    float v = 0.0f;
    if (o < OO) {
        float sv;
        const int idx = (b * OO + o) * DD + d;
        if constexpr (FUSED) {
            sv = 0.0f;
            #pragma unroll 8
            for (int ic = 0; ic < IC; ic++) sv += src[(size_t)ic * BOD + idx];
        } else {
            sv = src[idx];
        }
        const float sn = dred16(sv * sv);
        v = sv * (sn / ((1.0f + sn) * sqrtf(sn)));
        out[BB * DD + idx] = v;
        if (d == 0) norml[o] = sn;  // argmax(softmax(sqrt(sn))) == argmax(sn)
    }
    __syncthreads();

    int idx = 0;
    float best = norml[0];
    #pragma unroll
    for (int oo = 1; oo < OO; oo++) {
        const float n = norml[oo];
        if (n > best) { best = n; idx = oo; }
    }
    if (o == idx) out[b * DD + d] = v;
}

extern "C" void kernel_launch(void* const* d_in, const int* in_sizes, int n_in,
                              void* d_out, int out_size, void* d_ws, size_t ws_size,
                              hipStream_t stream) {
    const float* x = (const float*)d_in[0];  // [512,1152,8]
    const float* W = (const float*)d_in[1];  // [10,1152,16,8]
    float* out = (float*)d_out;              // [512*16 t] ++ [512*10*16 outputs]

    constexpr int ICP = 128;                 // i-chunks, partial-store path
    const size_t needP = ((size_t)ICP * BOD + 2 * BOD) * sizeof(float);

    if (ws_size >= needP) {
        // Atomic-free path: partials + streaming reduces, full occupancy.
        float* P  = (float*)d_ws;            // [ICP][B*O*D]
        float* s0 = P + (size_t)ICP * BOD;
        float* s1 = s0 + BOD;
        constexpr int NB = (BB / GB) * ICP;  // 2048 blocks = 8/CU

        caps_pass<0, ICP, 8, false><<<NB, 256, 0, stream>>>(x, W, P, nullptr, nullptr);
        caps_reduce<ICP><<<BOD / 256, 256, 0, stream>>>(P, s0, 0.1f);
        caps_pass<1, ICP, 8, false><<<NB, 256, 0, stream>>>(x, W, P, s0, nullptr);
        caps_reduce<ICP><<<BOD / 256, 256, 0, stream>>>(P, s1, 1.0f);
        caps_pass<2, ICP, 8, false><<<NB, 256, 0, stream>>>(x, W, P, s0, s1);
        caps_final<ICP, true><<<BB, 192, 0, stream>>>(P, out);
    } else {
        // Fallback (small ws): round-4 atomic path.
        constexpr int ICA = 64;
        float* s0 = (float*)d_ws;
        float* s1 = s0 + BOD;
        float* s2 = s1 + BOD;
        constexpr int NB = (BB / GB) * ICA;

        hipMemsetAsync(d_ws, 0, (size_t)3 * BOD * sizeof(float), stream);
        caps_pass<0, ICA, 4, true><<<NB, 256, 0, stream>>>(x, W, s0, nullptr, nullptr);
        caps_pass<1, ICA, 4, true><<<NB, 256, 0, stream>>>(x, W, s1, s0, nullptr);
        caps_pass<2, ICA, 4, true><<<NB, 256, 0, stream>>>(x, W, s2, s0, s1);
        caps_final<1, false><<<BB, 192, 0, stream>>>(s2, out);
    }
}

// Round 6
// 360.915 us; speedup vs baseline: 1.4374x; 1.4374x over previous
//
#include <hip/hip_runtime.h>

// Problem constants (B,O,I,D_out,D_in) = (512,10,1152,16,8)
#define BB 512
#define OO 10
#define II 1152
#define DD 16
#define EE 8
#define GB 32              // batches per block: 16 g-threads x 2 batches each
#define BOD (BB * OO * DD) // 81920 elements of s[b,o,d]
#define WSLAB (II * DD * EE / 4) // float4s per o-slab of W

typedef float v2f __attribute__((ext_vector_type(2)));
typedef float v4f __attribute__((ext_vector_type(4)));

// Packed fp32 math (VOP3P; plain VALU, no DPP hazards).
__device__ __forceinline__ v2f pk_mul(v2f a, v2f b) {
    v2f d;
    asm("v_pk_mul_f32 %0, %1, %2" : "=v"(d) : "v"(a), "v"(b));
    return d;
}
__device__ __forceinline__ v2f pk_fma(v2f a, v2f b, v2f c) {
    v2f d;
    asm("v_pk_fma_f32 %0, %1, %2, %3" : "=v"(d) : "v"(a), "v"(b), "v"(c));
    return d;
}

// 8-element dot: W row (2 float4) . x row (2 float4).
__device__ __forceinline__ float dot8(v4f wa, v4f wb, v4f xa, v4f xb) {
    v2f p = pk_mul(wa.lo, xa.lo);
    p = pk_fma(wa.hi, xa.hi, p);
    p = pk_fma(wb.lo, xb.lo, p);
    p = pk_fma(wb.hi, xb.hi, p);
    return p.x + p.y;
}

// One DPP-shuffled add; compiler inserts required DPP hazard NOPs.
template <int CTRL>
__device__ __forceinline__ float dpp_add(float v) {
    int s = __builtin_amdgcn_update_dpp(0, __float_as_int(v), CTRL, 0xf, 0xf, true);
    return v + __int_as_float(s);
}
// Butterfly sum across the 16-lane d-group (d = lane&15), pure VALU.
__device__ __forceinline__ float dred16(float v) {
    v = dpp_add<0xB1>(v);    // xor1 (quad_perm[1,0,3,2])
    v = dpp_add<0x4E>(v);    // xor2 (quad_perm[2,3,0,1])
    v = dpp_add<0x141>(v);   // row_half_mirror == xor4 after 4-lane uniformity
    v = dpp_add<0x140>(v);   // row_mirror == xor8 after 8-lane uniformity
    return v;
}

__device__ __forceinline__ float squash_lane(float sv) {
    float sn = dred16(sv * sv);
    return sv * (sn / ((1.0f + sn) * sqrtf(sn)));
}

// One routing pass over an i-chunk. PASS=0: uniform c -> s. PASS=1: b=<v0,xh>.
// PASS=2: b=<v0+v1,xh>. Each thread owns 2 batches (b0, b0+16).
// Grid = 16 batch-groups (low 4 bits) x IC i-chunks (high bits).
// ATOMIC=false: plain-store partials to s_out[ic*BOD + ...] (reduced later).
template <int PASS, int IC, int MINW, bool ATOMIC>
__global__ __launch_bounds__(256, MINW)
void caps_pass(const float* __restrict__ x, const float* __restrict__ W,
               float* __restrict__ s_out,
               const float* __restrict__ s0, const float* __restrict__ s1) {
    constexpr int ILEN = II / IC;
    constexpr int XROW = ILEN * 2 + 1;   // padded LDS row stride (float4s)
    __shared__ v4f xlds[GB * XROW];

    const int tid = threadIdx.x;
    const int d = tid & 15;
    const int g = tid >> 4;             // 0..15
    const int bg = blockIdx.x & 15;     // batch group
    const int ic = blockIdx.x >> 4;     // i-chunk
    const int b0 = bg * GB + g;
    const int b1 = b0 + 16;
    const int i0 = ic * ILEN;

    // Stage x[bg*32 .. +31][i0 .. i0+ILEN-1][:] into LDS (coalesced float4)
    const v4f* x4 = (const v4f*)x;
    for (int k = tid; k < GB * ILEN * 2; k += 256) {
        const int gg = k / (ILEN * 2);
        const int rem = k - gg * (ILEN * 2);
        xlds[gg * XROW + rem] =
            x4[(size_t)(bg * GB + gg) * (II * EE / 4) + (size_t)i0 * 2 + rem];
    }

    constexpr float LOG2E = 1.44269504f;
    // vr = log2(e) * (squash(s0) [+ squash(s1)]) so softmax uses exp2 directly.
    float vr0[OO], vr1[OO];
    if constexpr (PASS >= 1) {
        #pragma unroll
        for (int o = 0; o < OO; o++) {
            float v = squash_lane(s0[(b0 * OO + o) * DD + d]);
            float w = squash_lane(s0[(b1 * OO + o) * DD + d]);
            if constexpr (PASS == 2) {
                v += squash_lane(s1[(b0 * OO + o) * DD + d]);
                w += squash_lane(s1[(b1 * OO + o) * DD + d]);
            }
            vr0[o] = v * LOG2E;
            vr1[o] = w * LOG2E;
        }
    }
    __syncthreads();

    float sa0[OO], sa1[OO];
    #pragma unroll
    for (int o = 0; o < OO; o++) { sa0[o] = 0.0f; sa1[o] = 0.0f; }

    const v4f* W4 = (const v4f*)W;
    int widx = (i0 * DD + d) * 2;   // float4 index inside an o-slab

    for (int ii = 0; ii < ILEN; ii++) {
        const v4f xa0 = xlds[g * XROW + ii * 2 + 0];
        const v4f xb0 = xlds[g * XROW + ii * 2 + 1];
        const v4f xa1 = xlds[(g + 16) * XROW + ii * 2 + 0];
        const v4f xb1 = xlds[(g + 16) * XROW + ii * 2 + 1];

        float xh0[OO], xh1[OO];
        #pragma unroll
        for (int o = 0; o < OO; o++) {
            const v4f wa = W4[o * WSLAB + widx];
            const v4f wb = W4[o * WSLAB + widx + 1];
            xh0[o] = dot8(wa, wb, xa0, xb0);  // W reused for both batches
            xh1[o] = dot8(wa, wb, xa1, xb1);
        }

        if constexpr (PASS == 0) {
            #pragma unroll
            for (int o = 0; o < OO; o++) { sa0[o] += xh0[o]; sa1[o] += xh1[o]; }
        } else {
            float e0[OO], e1[OO];
            float se0 = 0.0f, se1 = 0.0f;
            #pragma unroll
            for (int o = 0; o < OO; o++) {
                e0[o] = __builtin_amdgcn_exp2f(dred16(vr0[o] * xh0[o]));
                e1[o] = __builtin_amdgcn_exp2f(dred16(vr1[o] * xh1[o]));
                se0 += e0[o];
                se1 += e1[o];
            }
            const float inv0 = __builtin_amdgcn_rcpf(se0);
            const float inv1 = __builtin_amdgcn_rcpf(se1);
            #pragma unroll
            for (int o = 0; o < OO; o++) {
                sa0[o] = fmaf(e0[o] * inv0, xh0[o], sa0[o]);
                sa1[o] = fmaf(e1[o] * inv1, xh1[o], sa1[o]);
            }
        }
        widx += DD * 2;
    }

    if constexpr (ATOMIC) {
        const float scale = (PASS == 0) ? 0.1f : 1.0f;
        #pragma unroll
        for (int o = 0; o < OO; o++) {
            atomicAdd(&s_out[(b0 * OO + o) * DD + d], sa0[o] * scale);
            atomicAdd(&s_out[(b1 * OO + o) * DD + d], sa1[o] * scale);
        }
    } else {
        float* P = s_out + (size_t)ic * BOD;
        #pragma unroll
        for (int o = 0; o < OO; o++) {
            P[(b0 * OO + o) * DD + d] = sa0[o];
            P[(b1 * OO + o) * DD + d] = sa1[o];
        }
    }
}

// Reduce partials: s[idx] = scale * sum_ic P[ic][idx]. Deterministic, streaming.
template <int IC>
__global__ __launch_bounds__(256)
void caps_reduce(const float* __restrict__ P, float* __restrict__ s, float scale) {
    const int idx = blockIdx.x * 256 + threadIdx.x;
    float a = 0.0f;
    #pragma unroll 8
    for (int ic = 0; ic < IC; ic++) a += P[(size_t)ic * BOD + idx];
    s[idx] = a * scale;
}

// Finalize: outputs = squash(s2); idx = argmax_o ||outputs||; t = outputs[idx].
// FUSED: src is the partial array (reduce s2 on the fly); else src is dense s2.
// d_out layout: t [B,1,16] flat first, then outputs [B,10,16].
template <int IC, bool FUSED>
__global__ __launch_bounds__(192)
void caps_final(const float* __restrict__ src, float* __restrict__ out) {
    __shared__ float norml[12];
    const int b = blockIdx.x;
    const int tid = threadIdx.x;
    const int d = tid & 15;
    const int o = tid >> 4;  // 0..11, active o<10

    float v = 0.0f;
    if (o < OO) {
        float sv;
        const int idx = (b * OO + o) * DD + d;
        if constexpr (FUSED) {
            sv = 0.0f;
            #pragma unroll 8
            for (int ic = 0; ic < IC; ic++) sv += src[(size_t)ic * BOD + idx];
        } else {
            sv = src[idx];
        }
        const float sn = dred16(sv * sv);
        v = sv * (sn / ((1.0f + sn) * sqrtf(sn)));
        out[BB * DD + idx] = v;
        if (d == 0) norml[o] = sn;  // argmax(softmax(sqrt(sn))) == argmax(sn)
    }
    __syncthreads();

    int idx = 0;
    float best = norml[0];
    #pragma unroll
    for (int oo = 1; oo < OO; oo++) {
        const float n = norml[oo];
        if (n > best) { best = n; idx = oo; }
    }
    if (o == idx) out[b * DD + d] = v;
}

extern "C" void kernel_launch(void* const* d_in, const int* in_sizes, int n_in,
                              void* d_out, int out_size, void* d_ws, size_t ws_size,
                              hipStream_t stream) {
    const float* x = (const float*)d_in[0];  // [512,1152,8]
    const float* W = (const float*)d_in[1];  // [10,1152,16,8]
    float* out = (float*)d_out;              // [512*16 t] ++ [512*10*16 outputs]

    constexpr int ICP = 96;                  // i-chunks: 16 bg x 96 ic = 1536 = 6/CU
    const size_t needP = ((size_t)ICP * BOD + 2 * BOD) * sizeof(float);

    if (ws_size >= needP) {
        // Atomic-free path: partials + streaming reduces. lb(256,6) caps VGPR at 85
        // (>64 proven need in round 4 -> no spill), 24 waves/CU.
        float* P  = (float*)d_ws;            // [ICP][B*O*D]
        float* s0 = P + (size_t)ICP * BOD;
        float* s1 = s0 + BOD;
        constexpr int NB = 16 * ICP;         // 1536 blocks = 6/CU

        caps_pass<0, ICP, 6, false><<<NB, 256, 0, stream>>>(x, W, P, nullptr, nullptr);
        caps_reduce<ICP><<<BOD / 256, 256, 0, stream>>>(P, s0, 0.1f);
        caps_pass<1, ICP, 6, false><<<NB, 256, 0, stream>>>(x, W, P, s0, nullptr);
        caps_reduce<ICP><<<BOD / 256, 256, 0, stream>>>(P, s1, 1.0f);
        caps_pass<2, ICP, 6, false><<<NB, 256, 0, stream>>>(x, W, P, s0, s1);
        caps_final<ICP, true><<<BB, 192, 0, stream>>>(P, out);
    } else {
        // Fallback (small ws): round-4 atomic path.
        constexpr int ICA = 64;
        float* s0 = (float*)d_ws;
        float* s1 = s0 + BOD;
        float* s2 = s1 + BOD;
        constexpr int NB = 16 * ICA;

        hipMemsetAsync(d_ws, 0, (size_t)3 * BOD * sizeof(float), stream);
        caps_pass<0, ICA, 4, true><<<NB, 256, 0, stream>>>(x, W, s0, nullptr, nullptr);
        caps_pass<1, ICA, 4, true><<<NB, 256, 0, stream>>>(x, W, s1, s0, nullptr);
        caps_pass<2, ICA, 4, true><<<NB, 256, 0, stream>>>(x, W, s2, s0, s1);
        caps_final<1, false><<<BB, 192, 0, stream>>>(s2, out);
    }
}

// Round 7
// 271.537 us; speedup vs baseline: 1.9105x; 1.3292x over previous
//
#include <hip/hip_runtime.h>

// Problem constants (B,O,I,D_out,D_in) = (512,10,1152,16,8)
#define BB 512
#define OO 10
#define II 1152
#define DD 16
#define EE 8
#define GB 32              // batches per block: 16 g-threads x 2 batches each
#define BOD (BB * OO * DD) // 81920 elements of s[b,o,d]
#define WSLAB (II * DD * EE / 4) // float4s per o-slab of W

typedef float v2f __attribute__((ext_vector_type(2)));
typedef float v4f __attribute__((ext_vector_type(4)));

// Packed fp32 math (VOP3P; plain VALU, no DPP hazards).
__device__ __forceinline__ v2f pk_mul(v2f a, v2f b) {
    v2f d;
    asm("v_pk_mul_f32 %0, %1, %2" : "=v"(d) : "v"(a), "v"(b));
    return d;
}
__device__ __forceinline__ v2f pk_fma(v2f a, v2f b, v2f c) {
    v2f d;
    asm("v_pk_fma_f32 %0, %1, %2, %3" : "=v"(d) : "v"(a), "v"(b), "v"(c));
    return d;
}

// 8-element dot: W row (2 float4) . x row (2 float4).
__device__ __forceinline__ float dot8(v4f wa, v4f wb, v4f xa, v4f xb) {
    v2f p = pk_mul(wa.lo, xa.lo);
    p = pk_fma(wa.hi, xa.hi, p);
    p = pk_fma(wb.lo, xb.lo, p);
    p = pk_fma(wb.hi, xb.hi, p);
    return p.x + p.y;
}

// One DPP-shuffled add; compiler inserts required DPP hazard NOPs.
template <int CTRL>
__device__ __forceinline__ float dpp_add(float v) {
    int s = __builtin_amdgcn_update_dpp(0, __float_as_int(v), CTRL, 0xf, 0xf, true);
    return v + __int_as_float(s);
}
// Butterfly sum across the 16-lane d-group (d = lane&15), pure VALU.
__device__ __forceinline__ float dred16(float v) {
    v = dpp_add<0xB1>(v);    // xor1 (quad_perm[1,0,3,2])
    v = dpp_add<0x4E>(v);    // xor2 (quad_perm[2,3,0,1])
    v = dpp_add<0x141>(v);   // row_half_mirror == xor4 after 4-lane uniformity
    v = dpp_add<0x140>(v);   // row_mirror == xor8 after 8-lane uniformity
    return v;
}

__device__ __forceinline__ float squash_lane(float sv) {
    float sn = dred16(sv * sv);
    return sv * (sn / ((1.0f + sn) * sqrtf(sn)));
}

// One routing pass over an i-chunk. PASS=0: uniform c -> s. PASS=1: b=<v0,xh>.
// PASS=2: b=<v0+v1,xh>. Each thread owns 2 batches (b0, b0+16).
// Grid = 16 batch-groups (low 4 bits) x IC i-chunks (high bits).
// ATOMIC=false: plain-store partials to s_out[ic*BOD + ...] (reduced later).
// NOTE: keep MINW=4 — min-wave hints >=6 provably make the allocator spill
// (rounds 5/6: VGPR 32/40, FETCH 395/193 MB). At MINW=4 this kernel lands on
// exactly 64 VGPR (round 4), and 64 VGPR allows 8 waves/SIMD in hardware.
template <int PASS, int IC, int MINW, bool ATOMIC>
__global__ __launch_bounds__(256, MINW)
void caps_pass(const float* __restrict__ x, const float* __restrict__ W,
               float* __restrict__ s_out,
               const float* __restrict__ s0, const float* __restrict__ s1) {
    constexpr int ILEN = II / IC;
    constexpr int XROW = ILEN * 2 + 1;   // padded LDS row stride (float4s)
    __shared__ v4f xlds[GB * XROW];

    const int tid = threadIdx.x;
    const int d = tid & 15;
    const int g = tid >> 4;             // 0..15
    const int bg = blockIdx.x & 15;     // batch group
    const int ic = blockIdx.x >> 4;     // i-chunk
    const int b0 = bg * GB + g;
    const int b1 = b0 + 16;
    const int i0 = ic * ILEN;

    // Stage x[bg*32 .. +31][i0 .. i0+ILEN-1][:] into LDS (coalesced float4)
    const v4f* x4 = (const v4f*)x;
    for (int k = tid; k < GB * ILEN * 2; k += 256) {
        const int gg = k / (ILEN * 2);
        const int rem = k - gg * (ILEN * 2);
        xlds[gg * XROW + rem] =
            x4[(size_t)(bg * GB + gg) * (II * EE / 4) + (size_t)i0 * 2 + rem];
    }

    constexpr float LOG2E = 1.44269504f;
    // vr = log2(e) * (squash(s0) [+ squash(s1)]) so softmax uses exp2 directly.
    float vr0[OO], vr1[OO];
    if constexpr (PASS >= 1) {
        #pragma unroll
        for (int o = 0; o < OO; o++) {
            float v = squash_lane(s0[(b0 * OO + o) * DD + d]);
            float w = squash_lane(s0[(b1 * OO + o) * DD + d]);
            if constexpr (PASS == 2) {
                v += squash_lane(s1[(b0 * OO + o) * DD + d]);
                w += squash_lane(s1[(b1 * OO + o) * DD + d]);
            }
            vr0[o] = v * LOG2E;
            vr1[o] = w * LOG2E;
        }
    }
    __syncthreads();

    float sa0[OO], sa1[OO];
    #pragma unroll
    for (int o = 0; o < OO; o++) { sa0[o] = 0.0f; sa1[o] = 0.0f; }

    const v4f* W4 = (const v4f*)W;
    int widx = (i0 * DD + d) * 2;   // float4 index inside an o-slab

    for (int ii = 0; ii < ILEN; ii++) {
        const v4f xa0 = xlds[g * XROW + ii * 2 + 0];
        const v4f xb0 = xlds[g * XROW + ii * 2 + 1];
        const v4f xa1 = xlds[(g + 16) * XROW + ii * 2 + 0];
        const v4f xb1 = xlds[(g + 16) * XROW + ii * 2 + 1];

        float xh0[OO], xh1[OO];
        #pragma unroll
        for (int o = 0; o < OO; o++) {
            const v4f wa = W4[o * WSLAB + widx];
            const v4f wb = W4[o * WSLAB + widx + 1];
            xh0[o] = dot8(wa, wb, xa0, xb0);  // W reused for both batches
            xh1[o] = dot8(wa, wb, xa1, xb1);
        }

        if constexpr (PASS == 0) {
            #pragma unroll
            for (int o = 0; o < OO; o++) { sa0[o] += xh0[o]; sa1[o] += xh1[o]; }
        } else {
            float e0[OO], e1[OO];
            float se0 = 0.0f, se1 = 0.0f;
            #pragma unroll
            for (int o = 0; o < OO; o++) {
                e0[o] = __builtin_amdgcn_exp2f(dred16(vr0[o] * xh0[o]));
                e1[o] = __builtin_amdgcn_exp2f(dred16(vr1[o] * xh1[o]));
                se0 += e0[o];
                se1 += e1[o];
            }
            const float inv0 = __builtin_amdgcn_rcpf(se0);
            const float inv1 = __builtin_amdgcn_rcpf(se1);
            #pragma unroll
            for (int o = 0; o < OO; o++) {
                sa0[o] = fmaf(e0[o] * inv0, xh0[o], sa0[o]);
                sa1[o] = fmaf(e1[o] * inv1, xh1[o], sa1[o]);
            }
        }
        widx += DD * 2;
    }

    if constexpr (ATOMIC) {
        const float scale = (PASS == 0) ? 0.1f : 1.0f;
        #pragma unroll
        for (int o = 0; o < OO; o++) {
            atomicAdd(&s_out[(b0 * OO + o) * DD + d], sa0[o] * scale);
            atomicAdd(&s_out[(b1 * OO + o) * DD + d], sa1[o] * scale);
        }
    } else {
        float* P = s_out + (size_t)ic * BOD;
        #pragma unroll
        for (int o = 0; o < OO; o++) {
            P[(b0 * OO + o) * DD + d] = sa0[o];
            P[(b1 * OO + o) * DD + d] = sa1[o];
        }
    }
}

// Reduce partials: s[idx] = scale * sum_ic P[ic][idx]. Deterministic, streaming.
template <int IC>
__global__ __launch_bounds__(256)
void caps_reduce(const float* __restrict__ P, float* __restrict__ s, float scale) {
    const int idx = blockIdx.x * 256 + threadIdx.x;
    float a = 0.0f;
    #pragma unroll 8
    for (int ic = 0; ic < IC; ic++) a += P[(size_t)ic * BOD + idx];
    s[idx] = a * scale;
}

// Finalize: outputs = squash(s2); idx = argmax_o ||outputs||; t = outputs[idx].
// FUSED: src is the partial array (reduce s2 on the fly); else src is dense s2.
// d_out layout: t [B,1,16] flat first, then outputs [B,10,16].
template <int IC, bool FUSED>
__global__ __launch_bounds__(192)
void caps_final(const float* __restrict__ src, float* __restrict__ out) {
    __shared__ float norml[12];
    const int b = blockIdx.x;
    const int tid = threadIdx.x;
    const int d = tid & 15;
    const int o = tid >> 4;  // 0..11, active o<10

    float v = 0.0f;
    if (o < OO) {
        float sv;
        const int idx = (b * OO + o) * DD + d;
        if constexpr (FUSED) {
            sv = 0.0f;
            #pragma unroll 8
            for (int ic = 0; ic < IC; ic++) sv += src[(size_t)ic * BOD + idx];
        } else {
            sv = src[idx];
        }
        const float sn = dred16(sv * sv);
        v = sv * (sn / ((1.0f + sn) * sqrtf(sn)));
        out[BB * DD + idx] = v;
        if (d == 0) norml[o] = sn;  // argmax(softmax(sqrt(sn))) == argmax(sn)
    }
    __syncthreads();

    int idx = 0;
    float best = norml[0];
    #pragma unroll
    for (int oo = 1; oo < OO; oo++) {
        const float n = norml[oo];
        if (n > best) { best = n; idx = oo; }
    }
    if (o == idx) out[b * DD + d] = v;
}

extern "C" void kernel_launch(void* const* d_in, const int* in_sizes, int n_in,
                              void* d_out, int out_size, void* d_ws, size_t ws_size,
                              hipStream_t stream) {
    const float* x = (const float*)d_in[0];  // [512,1152,8]
    const float* W = (const float*)d_in[1];  // [10,1152,16,8]
    float* out = (float*)d_out;              // [512*16 t] ++ [512*10*16 outputs]

    constexpr int ICP = 128;                 // 16 bg x 128 ic = 2048 blocks = 8/CU
    const size_t needP = ((size_t)ICP * BOD + 2 * BOD) * sizeof(float);

    if (ws_size >= needP) {
        // Atomic-free path: partials + streaming reduces. MINW stays 4 (see note).
        float* P  = (float*)d_ws;            // [ICP][B*O*D]
        float* s0 = P + (size_t)ICP * BOD;
        float* s1 = s0 + BOD;
        constexpr int NB = 16 * ICP;         // 2048 blocks

        caps_pass<0, ICP, 4, false><<<NB, 256, 0, stream>>>(x, W, P, nullptr, nullptr);
        caps_reduce<ICP><<<BOD / 256, 256, 0, stream>>>(P, s0, 0.1f);
        caps_pass<1, ICP, 4, false><<<NB, 256, 0, stream>>>(x, W, P, s0, nullptr);
        caps_reduce<ICP><<<BOD / 256, 256, 0, stream>>>(P, s1, 1.0f);
        caps_pass<2, ICP, 4, false><<<NB, 256, 0, stream>>>(x, W, P, s0, s1);
        caps_final<ICP, true><<<BB, 192, 0, stream>>>(P, out);
    } else {
        // Fallback (small ws): round-4 atomic path (proven 248 us).
        constexpr int ICA = 64;
        float* s0 = (float*)d_ws;
        float* s1 = s0 + BOD;
        float* s2 = s1 + BOD;
        constexpr int NB = 16 * ICA;

        hipMemsetAsync(d_ws, 0, (size_t)3 * BOD * sizeof(float), stream);
        caps_pass<0, ICA, 4, true><<<NB, 256, 0, stream>>>(x, W, s0, nullptr, nullptr);
        caps_pass<1, ICA, 4, true><<<NB, 256, 0, stream>>>(x, W, s1, s0, nullptr);
        caps_pass<2, ICA, 4, true><<<NB, 256, 0, stream>>>(x, W, s2, s0, s1);
        caps_final<1, false><<<BB, 192, 0, stream>>>(s2, out);
    }
}

// Round 8
// 271.184 us; speedup vs baseline: 1.9130x; 1.0013x over previous
//
#include <hip/hip_runtime.h>

// Problem constants (B,O,I,D_out,D_in) = (512,10,1152,16,8)
#define BB 512
#define OO 10
#define II 1152
#define DD 16
#define EE 8
#define GB 32              // batches per block: 16 g-threads x 2 batches each
#define BOD (BB * OO * DD) // 81920 elements of s[b,o,d]
#define WSLABB (II * DD * EE * 4) // BYTES per o-slab of W = 589824

typedef float v2f __attribute__((ext_vector_type(2)));
typedef float v4f __attribute__((ext_vector_type(4)));

// Packed fp32 math (VOP3P; plain VALU, no DPP hazards).
__device__ __forceinline__ v2f pk_mul(v2f a, v2f b) {
    v2f d;
    asm("v_pk_mul_f32 %0, %1, %2" : "=v"(d) : "v"(a), "v"(b));
    return d;
}
__device__ __forceinline__ v2f pk_fma(v2f a, v2f b, v2f c) {
    v2f d;
    asm("v_pk_fma_f32 %0, %1, %2, %3" : "=v"(d) : "v"(a), "v"(b), "v"(c));
    return d;
}

// 8-element dot: W row (2 float4) . x row (2 float4).
__device__ __forceinline__ float dot8(v4f wa, v4f wb, v4f xa, v4f xb) {
    v2f p = pk_mul(wa.lo, xa.lo);
    p = pk_fma(wa.hi, xa.hi, p);
    p = pk_fma(wb.lo, xb.lo, p);
    p = pk_fma(wb.hi, xb.hi, p);
    return p.x + p.y;
}

// One DPP-shuffled add; compiler inserts required DPP hazard NOPs.
template <int CTRL>
__device__ __forceinline__ float dpp_add(float v) {
    int s = __builtin_amdgcn_update_dpp(0, __float_as_int(v), CTRL, 0xf, 0xf, true);
    return v + __int_as_float(s);
}
// Butterfly sum across the 16-lane d-group (d = lane&15), pure VALU.
__device__ __forceinline__ float dred16(float v) {
    v = dpp_add<0xB1>(v);    // xor1 (quad_perm[1,0,3,2])
    v = dpp_add<0x4E>(v);    // xor2 (quad_perm[2,3,0,1])
    v = dpp_add<0x141>(v);   // row_half_mirror == xor4 after 4-lane uniformity
    v = dpp_add<0x140>(v);   // row_mirror == xor8 after 8-lane uniformity
    return v;
}

__device__ __forceinline__ float squash_lane(float sv) {
    float sn = dred16(sv * sv);
    return sv * (sn / ((1.0f + sn) * sqrtf(sn)));
}

// One routing pass over an i-chunk. PASS=0: uniform c -> s. PASS=1: b=<v0,xh>.
// PASS=2: b=<v0+v1,xh>. Each thread owns 2 batches (b0, b0+16).
// Grid = 16 batch-groups (low 4 bits) x IC i-chunks (high bits).
// ATOMIC=false: plain-store partials to s_out[ic*BOD + ...] (reduced later).
// NOTE: NO min-waves arg in launch_bounds. Evidence (rounds 1,3,4,7): with
// lb(256,N) occupancy pins at exactly N waves/EU (23% at N=2, 40% at N=4)
// regardless of grid/VGPR/LDS; N>=6 forces spills. The hint acts as a cap.
template <int PASS, int IC, bool ATOMIC>
__global__ __launch_bounds__(256)
void caps_pass(const float* __restrict__ x, const float* __restrict__ W,
               float* __restrict__ s_out,
               const float* __restrict__ s0, const float* __restrict__ s1) {
    constexpr int ILEN = II / IC;
    constexpr int XROW = ILEN * 2 + 1;   // padded LDS row stride (float4s)
    __shared__ v4f xlds[GB * XROW];

    const int tid = threadIdx.x;
    const int d = tid & 15;
    const int g = tid >> 4;                       // 0..15
    const int bg = blockIdx.x & 15;               // batch group
    const int ic = (blockIdx.x >> 4) & (IC - 1);  // i-chunk (masked: provable range)
    const int b0 = bg * GB + g;
    const int b1 = b0 + 16;
    const int i0 = ic * ILEN;

    // Stage x[bg*32 .. +31][i0 .. i0+ILEN-1][:] into LDS (coalesced float4)
    const v4f* x4 = (const v4f*)x;
    for (int k = tid; k < GB * ILEN * 2; k += 256) {
        const int gg = k / (ILEN * 2);
        const int rem = k - gg * (ILEN * 2);
        xlds[gg * XROW + rem] =
            x4[(size_t)(bg * GB + gg) * (II * EE / 4) + (size_t)i0 * 2 + rem];
    }

    constexpr float LOG2E = 1.44269504f;
    // vr = log2(e) * (squash(s0) [+ squash(s1)]) so softmax uses exp2 directly.
    float vr0[OO], vr1[OO];
    if constexpr (PASS >= 1) {
        #pragma unroll
        for (int o = 0; o < OO; o++) {
            float v = squash_lane(s0[(b0 * OO + o) * DD + d]);
            float w = squash_lane(s0[(b1 * OO + o) * DD + d]);
            if constexpr (PASS == 2) {
                v += squash_lane(s1[(b0 * OO + o) * DD + d]);
                w += squash_lane(s1[(b1 * OO + o) * DD + d]);
            }
            vr0[o] = v * LOG2E;
            vr1[o] = w * LOG2E;
        }
    }
    __syncthreads();

    float sa0[OO], sa1[OO];
    #pragma unroll
    for (int o = 0; o < OO; o++) { sa0[o] = 0.0f; sa1[o] = 0.0f; }

    // W addressing: uniform per-o base (SGPR candidate after unroll) + one
    // unsigned BYTE offset VGPR -> saddr-form global_load_dwordx4.
    const char* Wb = (const char*)W;
    unsigned wbyte = (unsigned)((i0 * DD + d) * 2) * 16u;  // < 589824, provable

    for (int ii = 0; ii < ILEN; ii++) {
        const v4f xa0 = xlds[g * XROW + ii * 2 + 0];
        const v4f xb0 = xlds[g * XROW + ii * 2 + 1];
        const v4f xa1 = xlds[(g + 16) * XROW + ii * 2 + 0];
        const v4f xb1 = xlds[(g + 16) * XROW + ii * 2 + 1];

        float xh0[OO], xh1[OO];
        #pragma unroll
        for (int o = 0; o < OO; o++) {
            const char* Wo = Wb + (size_t)o * WSLABB;   // uniform base
            const v4f wa = *(const v4f*)(Wo + wbyte);
            const v4f wb = *(const v4f*)(Wo + wbyte + 16);
            xh0[o] = dot8(wa, wb, xa0, xb0);  // W reused for both batches
            xh1[o] = dot8(wa, wb, xa1, xb1);
        }

        if constexpr (PASS == 0) {
            #pragma unroll
            for (int o = 0; o < OO; o++) { sa0[o] += xh0[o]; sa1[o] += xh1[o]; }
        } else {
            float e0[OO], e1[OO];
            float se0 = 0.0f, se1 = 0.0f;
            #pragma unroll
            for (int o = 0; o < OO; o++) {
                e0[o] = __builtin_amdgcn_exp2f(dred16(vr0[o] * xh0[o]));
                e1[o] = __builtin_amdgcn_exp2f(dred16(vr1[o] * xh1[o]));
                se0 += e0[o];
                se1 += e1[o];
            }
            const float inv0 = __builtin_amdgcn_rcpf(se0);
            const float inv1 = __builtin_amdgcn_rcpf(se1);
            #pragma unroll
            for (int o = 0; o < OO; o++) {
                sa0[o] = fmaf(e0[o] * inv0, xh0[o], sa0[o]);
                sa1[o] = fmaf(e1[o] * inv1, xh1[o], sa1[o]);
            }
        }
        wbyte += DD * 2 * 16;   // next i row
    }

    if constexpr (ATOMIC) {
        const float scale = (PASS == 0) ? 0.1f : 1.0f;
        #pragma unroll
        for (int o = 0; o < OO; o++) {
            atomicAdd(&s_out[(b0 * OO + o) * DD + d], sa0[o] * scale);
            atomicAdd(&s_out[(b1 * OO + o) * DD + d], sa1[o] * scale);
        }
    } else {
        float* P = s_out + (size_t)ic * BOD;
        #pragma unroll
        for (int o = 0; o < OO; o++) {
            P[(b0 * OO + o) * DD + d] = sa0[o];
            P[(b1 * OO + o) * DD + d] = sa1[o];
        }
    }
}

// Reduce partials: s[idx] = scale * sum_ic P[ic][idx]. Deterministic, streaming.
template <int IC>
__global__ __launch_bounds__(256)
void caps_reduce(const float* __restrict__ P, float* __restrict__ s, float scale) {
    const int idx = blockIdx.x * 256 + threadIdx.x;
    float a = 0.0f;
    #pragma unroll 8
    for (int ic = 0; ic < IC; ic++) a += P[(size_t)ic * BOD + idx];
    s[idx] = a * scale;
}

// Finalize: outputs = squash(s2); idx = argmax_o ||outputs||; t = outputs[idx].
// FUSED: src is the partial array (reduce s2 on the fly); else src is dense s2.
// d_out layout: t [B,1,16] flat first, then outputs [B,10,16].
template <int IC, bool FUSED>
__global__ __launch_bounds__(192)
void caps_final(const float* __restrict__ src, float* __restrict__ out) {
    __shared__ float norml[12];
    const int b = blockIdx.x;
    const int tid = threadIdx.x;
    const int d = tid & 15;
    const int o = tid >> 4;  // 0..11, active o<10

    float v = 0.0f;
    if (o < OO) {
        float sv;
        const int idx = (b * OO + o) * DD + d;
        if constexpr (FUSED) {
            sv = 0.0f;
            #pragma unroll 8
            for (int ic = 0; ic < IC; ic++) sv += src[(size_t)ic * BOD + idx];
        } else {
            sv = src[idx];
        }
        const float sn = dred16(sv * sv);
        v = sv * (sn / ((1.0f + sn) * sqrtf(sn)));
        out[BB * DD + idx] = v;
        if (d == 0) norml[o] = sn;  // argmax(softmax(sqrt(sn))) == argmax(sn)
    }
    __syncthreads();

    int idx = 0;
    float best = norml[0];
    #pragma unroll
    for (int oo = 1; oo < OO; oo++) {
        const float n = norml[oo];
        if (n > best) { best = n; idx = oo; }
    }
    if (o == idx) out[b * DD + d] = v;
}

extern "C" void kernel_launch(void* const* d_in, const int* in_sizes, int n_in,
                              void* d_out, int out_size, void* d_ws, size_t ws_size,
                              hipStream_t stream) {
    const float* x = (const float*)d_in[0];  // [512,1152,8]
    const float* W = (const float*)d_in[1];  // [10,1152,16,8]
    float* out = (float*)d_out;              // [512*16 t] ++ [512*10*16 outputs]

    constexpr int ICP = 128;                 // 16 bg x 128 ic = 2048 blocks = 8/CU
    const size_t needP = ((size_t)ICP * BOD + 2 * BOD) * sizeof(float);

    if (ws_size >= needP) {
        // Atomic-free path: partials + streaming reduces.
        float* P  = (float*)d_ws;            // [ICP][B*O*D]
        float* s0 = P + (size_t)ICP * BOD;
        float* s1 = s0 + BOD;
        constexpr int NB = 16 * ICP;         // 2048 blocks

        caps_pass<0, ICP, false><<<NB, 256, 0, stream>>>(x, W, P, nullptr, nullptr);
        caps_reduce<ICP><<<BOD / 256, 256, 0, stream>>>(P, s0, 0.1f);
        caps_pass<1, ICP, false><<<NB, 256, 0, stream>>>(x, W, P, s0, nullptr);
        caps_reduce<ICP><<<BOD / 256, 256, 0, stream>>>(P, s1, 1.0f);
        caps_pass<2, ICP, false><<<NB, 256, 0, stream>>>(x, W, P, s0, s1);
        caps_final<ICP, true><<<BB, 192, 0, stream>>>(P, out);
    } else {
        // Fallback (small ws): atomic path.
        constexpr int ICA = 64;
        float* s0 = (float*)d_ws;
        float* s1 = s0 + BOD;
        float* s2 = s1 + BOD;
        constexpr int NB = 16 * ICA;

        hipMemsetAsync(d_ws, 0, (size_t)3 * BOD * sizeof(float), stream);
        caps_pass<0, ICA, true><<<NB, 256, 0, stream>>>(x, W, s0, nullptr, nullptr);
        caps_pass<1, ICA, true><<<NB, 256, 0, stream>>>(x, W, s1, s0, nullptr);
        caps_pass<2, ICA, true><<<NB, 256, 0, stream>>>(x, W, s2, s0, s1);
        caps_final<1, false><<<BB, 192, 0, stream>>>(s2, out);
    }
}

// Round 9
// 266.422 us; speedup vs baseline: 1.9472x; 1.0179x over previous
//
#include <hip/hip_runtime.h>

// Problem constants (B,O,I,D_out,D_in) = (512,10,1152,16,8)
#define BB 512
#define OO 10
#define II 1152
#define DD 16
#define EE 8
#define BOD (BB * OO * DD)        // 81920 elements of s[b,o,d]
#define WSLABB (II * DD * EE * 4) // bytes per o-slab of W = 589824

// Geometry: 512-thread blocks (8 waves). d = tid&15, g = tid>>4 -> 32 batches.
// Block owns an 18-i chunk = 3 staged sub-chunks of 6 i. W sub-slice in LDS.
#define TPB 512
#define GB 32
#define ISUB 6                 // i's per staged W sub-chunk
#define NSUB 3                 // sub-chunks per block
#define ILEN (ISUB * NSUB)     // 18 i's per block
#define ICN (II / ILEN)        // 64 outer i-chunks
#define NUNITS (OO * ISUB)     // 60 LDS units of 512 B
#define WBYTES (NUNITS * 512)  // 30720 B LDS per block

typedef float v2f __attribute__((ext_vector_type(2)));
typedef float v4f __attribute__((ext_vector_type(4)));

// Packed fp32 math (VOP3P; plain VALU, no DPP hazards).
__device__ __forceinline__ v2f pk_mul(v2f a, v2f b) {
    v2f d;
    asm("v_pk_mul_f32 %0, %1, %2" : "=v"(d) : "v"(a), "v"(b));
    return d;
}
__device__ __forceinline__ v2f pk_fma(v2f a, v2f b, v2f c) {
    v2f d;
    asm("v_pk_fma_f32 %0, %1, %2, %3" : "=v"(d) : "v"(a), "v"(b), "v"(c));
    return d;
}

// 8-element dot: W row (2 float4) . x row (2 float4).
__device__ __forceinline__ float dot8(v4f wa, v4f wb, v4f xa, v4f xb) {
    v2f p = pk_mul(wa.lo, xa.lo);
    p = pk_fma(wa.hi, xa.hi, p);
    p = pk_fma(wb.lo, xb.lo, p);
    p = pk_fma(wb.hi, xb.hi, p);
    return p.x + p.y;
}

// One DPP-shuffled add; compiler inserts required DPP hazard NOPs.
template <int CTRL>
__device__ __forceinline__ float dpp_add(float v) {
    int s = __builtin_amdgcn_update_dpp(0, __float_as_int(v), CTRL, 0xf, 0xf, true);
    return v + __int_as_float(s);
}
// Butterfly sum across the 16-lane d-group (d = lane&15), pure VALU.
__device__ __forceinline__ float dred16(float v) {
    v = dpp_add<0xB1>(v);    // xor1 (quad_perm[1,0,3,2])
    v = dpp_add<0x4E>(v);    // xor2 (quad_perm[2,3,0,1])
    v = dpp_add<0x141>(v);   // row_half_mirror == xor4 after 4-lane uniformity
    v = dpp_add<0x140>(v);   // row_mirror == xor8 after 8-lane uniformity
    return v;
}

__device__ __forceinline__ float squash_lane(float sv) {
    float sn = dred16(sv * sv);
    return sv * (sn / ((1.0f + sn) * sqrtf(sn)));
}

// One routing pass. PASS=0: uniform c -> s. PASS=1: b=<v0,xh>. PASS=2: b=<v0+v1,xh>.
// Each thread owns 1 batch (b = bg*32 + g) and 1 output dim d.
// W sub-slice lives in LDS, permuted layout: unit u=(o*ISUB+ii) of 512 B holds
// [h][d][16B] so ds_read_b128 at d*16 is 2-way bank-free and g-broadcast.
// Grid = 16 batch-groups (low 4 bits) x ICN i-chunks (high bits).
template <int PASS, bool ATOMIC>
__global__ __launch_bounds__(TPB)
void caps_pass(const float* __restrict__ x, const float* __restrict__ W,
               float* __restrict__ s_out,
               const float* __restrict__ s0, const float* __restrict__ s1) {
    __shared__ char wlds[WBYTES];

    const int tid = threadIdx.x;
    const int d = tid & 15;
    const int g = tid >> 4;             // 0..31
    const int bg = blockIdx.x & 15;     // batch group
    const int ic = blockIdx.x >> 4;     // outer i-chunk 0..63
    const int b = bg * GB + g;
    const int i0 = ic * ILEN;

    constexpr float LOG2E = 1.44269504f;
    // vr = log2(e) * (squash(s0) [+ squash(s1)]) so softmax uses exp2 directly.
    float vr[OO];
    if constexpr (PASS >= 1) {
        #pragma unroll
        for (int o = 0; o < OO; o++) {
            float v = squash_lane(s0[(b * OO + o) * DD + d]);
            if constexpr (PASS == 2) v += squash_lane(s1[(b * OO + o) * DD + d]);
            vr[o] = v * LOG2E;
        }
    }

    float sacc[OO];
    #pragma unroll
    for (int o = 0; o < OO; o++) sacc[o] = 0.0f;

    const char* xrow = (const char*)x + ((size_t)b * II + i0) * (EE * 4);

    for (int s = 0; s < NSUB; s++) {
        if (s) __syncthreads();   // prior sub-chunk fully consumed
        // Stage W[o][i0+s*6 .. +6)[d][e] -> wlds, permuted: lds byte k*16 holds
        // (u=k>>5, h=(k>>4)&1, dd=k&15) = global W + o*SLAB + ii*512 + dd*32 + h*16.
        {
            const char* Wg = (const char*)W + (size_t)(i0 + s * ISUB) * 512;
            for (int k = tid; k < NUNITS * 32; k += TPB) {
                const int u  = k >> 5;
                const int o  = u / ISUB;
                const int ii = u - o * ISUB;
                const int sl = k & 31;
                const v4f w = *(const v4f*)(Wg + (size_t)o * WSLABB + ii * 512
                                            + (sl & 15) * 32 + (sl >> 4) * 16);
                *(v4f*)(wlds + k * 16) = w;
            }
        }
        __syncthreads();

        const char* xs = xrow + s * ISUB * 32;
        const char* wd = wlds + (d << 4);   // loop-invariant LDS base; rest is imm
        #pragma unroll
        for (int ii = 0; ii < ISUB; ii++) {
            const v4f xa = *(const v4f*)(xs + ii * 32);
            const v4f xb = *(const v4f*)(xs + ii * 32 + 16);

            float xh[OO];
            #pragma unroll
            for (int o = 0; o < OO; o++) {
                const v4f wa = *(const v4f*)(wd + (o * ISUB + ii) * 512);
                const v4f wb = *(const v4f*)(wd + (o * ISUB + ii) * 512 + 256);
                xh[o] = dot8(wa, wb, xa, xb);
            }

            if constexpr (PASS == 0) {
                #pragma unroll
                for (int o = 0; o < OO; o++) sacc[o] += xh[o];
            } else {
                float e[OO];
                float se = 0.0f;
                #pragma unroll
                for (int o = 0; o < OO; o++) {
                    e[o] = __builtin_amdgcn_exp2f(dred16(vr[o] * xh[o]));
                    se += e[o];
                }
                const float inv = __builtin_amdgcn_rcpf(se);
                #pragma unroll
                for (int o = 0; o < OO; o++)
                    sacc[o] = fmaf(e[o] * inv, xh[o], sacc[o]);
            }
        }
    }

    if constexpr (ATOMIC) {
        const float scale = (PASS == 0) ? 0.1f : 1.0f;
        #pragma unroll
        for (int o = 0; o < OO; o++)
            atomicAdd(&s_out[(b * OO + o) * DD + d], sacc[o] * scale);
    } else {
        float* P = s_out + (size_t)ic * BOD;
        #pragma unroll
        for (int o = 0; o < OO; o++)
            P[(b * OO + o) * DD + d] = sacc[o];
    }
}

// Reduce partials: s[idx] = scale * sum_ic P[ic][idx]. Deterministic, streaming.
template <int IC>
__global__ __launch_bounds__(256)
void caps_reduce(const float* __restrict__ P, float* __restrict__ s, float scale) {
    const int idx = blockIdx.x * 256 + threadIdx.x;
    float a = 0.0f;
    #pragma unroll 8
    for (int ic = 0; ic < IC; ic++) a += P[(size_t)ic * BOD + idx];
    s[idx] = a * scale;
}

// Finalize: outputs = squash(s2); idx = argmax_o ||outputs||; t = outputs[idx].
// FUSED: src is the partial array (reduce s2 on the fly); else src is dense s2.
// d_out layout: t [B,1,16] flat first, then outputs [B,10,16].
template <int IC, bool FUSED>
__global__ __launch_bounds__(192)
void caps_final(const float* __restrict__ src, float* __restrict__ out) {
    __shared__ float norml[12];
    const int b = blockIdx.x;
    const int tid = threadIdx.x;
    const int d = tid & 15;
    const int o = tid >> 4;  // 0..11, active o<10

    float v = 0.0f;
    if (o < OO) {
        float sv;
        const int idx = (b * OO + o) * DD + d;
        if constexpr (FUSED) {
            sv = 0.0f;
            #pragma unroll 8
            for (int ic = 0; ic < IC; ic++) sv += src[(size_t)ic * BOD + idx];
        } else {
            sv = src[idx];
        }
        const float sn = dred16(sv * sv);
        v = sv * (sn / ((1.0f + sn) * sqrtf(sn)));
        out[BB * DD + idx] = v;
        if (d == 0) norml[o] = sn;  // argmax(softmax(sqrt(sn))) == argmax(sn)
    }
    __syncthreads();

    int idx = 0;
    float best = norml[0];
    #pragma unroll
    for (int oo = 1; oo < OO; oo++) {
        const float n = norml[oo];
        if (n > best) { best = n; idx = oo; }
    }
    if (o == idx) out[b * DD + d] = v;
}

extern "C" void kernel_launch(void* const* d_in, const int* in_sizes, int n_in,
                              void* d_out, int out_size, void* d_ws, size_t ws_size,
                              hipStream_t stream) {
    const float* x = (const float*)d_in[0];  // [512,1152,8]
    const float* W = (const float*)d_in[1];  // [10,1152,16,8]
    float* out = (float*)d_out;              // [512*16 t] ++ [512*10*16 outputs]

    constexpr int NB = 16 * ICN;             // 1024 blocks x 8 waves = 32 waves/CU
    const size_t needP = ((size_t)ICN * BOD + 2 * BOD) * sizeof(float);  // ~21.6 MB

    if (ws_size >= needP) {
        // Atomic-free path: partials + streaming reduces.
        float* P  = (float*)d_ws;            // [ICN][B*O*D]
        float* s0 = P + (size_t)ICN * BOD;
        float* s1 = s0 + BOD;

        caps_pass<0, false><<<NB, TPB, 0, stream>>>(x, W, P, nullptr, nullptr);
        caps_reduce<ICN><<<BOD / 256, 256, 0, stream>>>(P, s0, 0.1f);
        caps_pass<1, false><<<NB, TPB, 0, stream>>>(x, W, P, s0, nullptr);
        caps_reduce<ICN><<<BOD / 256, 256, 0, stream>>>(P, s1, 1.0f);
        caps_pass<2, false><<<NB, TPB, 0, stream>>>(x, W, P, s0, s1);
        caps_final<ICN, true><<<BB, 192, 0, stream>>>(P, out);
    } else {
        // Fallback (tiny ws): same kernels, atomic accumulation.
        float* s0 = (float*)d_ws;
        float* s1 = s0 + BOD;
        float* s2 = s1 + BOD;

        hipMemsetAsync(d_ws, 0, (size_t)3 * BOD * sizeof(float), stream);
        caps_pass<0, true><<<NB, TPB, 0, stream>>>(x, W, s0, nullptr, nullptr);
        caps_pass<1, true><<<NB, TPB, 0, stream>>>(x, W, s1, s0, nullptr);
        caps_pass<2, true><<<NB, TPB, 0, stream>>>(x, W, s2, s0, s1);
        caps_final<1, false><<<BB, 192, 0, stream>>>(s2, out);
    }
}